// Round 2
// baseline (479.523 us; speedup 1.0000x reference)
//
#include <hip/hip_runtime.h>
#include <hip/hip_bf16.h>

#define LRELU(e) ((e) > 0.f ? (e) : 0.2f * (e))

typedef __attribute__((ext_vector_type(8))) short bf16x8;
typedef __attribute__((ext_vector_type(4))) float floatx4;

__device__ inline short f2bf(float f) {
    union { float f; unsigned u; } v; v.f = f;
    unsigned r = v.u + 0x7fffu + ((v.u >> 16) & 1u);
    return (short)(r >> 16);
}
__device__ inline float bflo(int p) {
    union { unsigned u; float f; } v; v.u = (unsigned)p << 16; return v.f;
}
__device__ inline float bfhi(int p) {
    union { unsigned u; float f; } v; v.u = (unsigned)p & 0xffff0000u; return v.f;
}
__device__ inline float bf2f(unsigned short s) {
    union { unsigned u; float f; } v; v.u = (unsigned)s << 16; return v.f;
}

// ---------------- CSR build + weight prep (incl. folded attention columns) ----------

__global__ void k_count_wprep(const int* __restrict__ dstE, int E, int N,
                              int* __restrict__ deg,
                              const float* __restrict__ W0, const float* __restrict__ W1,
                              const float* __restrict__ W2,
                              const float* __restrict__ as0, const float* __restrict__ ad0,
                              const float* __restrict__ as1, const float* __restrict__ ad1,
                              const float* __restrict__ as2, const float* __restrict__ ad2,
                              short* __restrict__ Wt0, short* __restrict__ Wt1,
                              short* __restrict__ Wt2) {
    int i = blockIdx.x * blockDim.x + threadIdx.x;
    if (i < E) atomicAdd(&deg[dstE[i]], 1);
    else if (i < E + N) atomicAdd(&deg[i - E], 1);

    if (i < 128 * 128) {
        int n = i >> 7, k = i & 127;
        Wt0[n * 128 + k] = f2bf(W0[k * 128 + n]);
        Wt1[n * 128 + k] = f2bf(W1[k * 128 + n]);
    } else if (i < 128 * 128 + 64 * 128) {
        int j = i - 128 * 128;
        int n = j >> 7, k = j & 127;
        Wt2[n * 128 + k] = f2bf(W2[k * 64 + n]);
    } else if (i < 128 * 128 + 64 * 128 + 128 * 8) {
        int j = i - (128 * 128 + 64 * 128);
        int k = j >> 3, h = j & 7;
        float s0 = 0.f, d0 = 0.f, s1 = 0.f, d1 = 0.f;
        #pragma unroll
        for (int d = 0; d < 16; d++) {
            float w0 = W0[k * 128 + h * 16 + d];
            float w1 = W1[k * 128 + h * 16 + d];
            s0 += w0 * as0[h * 16 + d];
            d0 += w0 * ad0[h * 16 + d];
            s1 += w1 * as1[h * 16 + d];
            d1 += w1 * ad1[h * 16 + d];
        }
        Wt0[(128 + h) * 128 + k] = f2bf(s0);
        Wt0[(136 + h) * 128 + k] = f2bf(d0);
        Wt1[(128 + h) * 128 + k] = f2bf(s1);
        Wt1[(136 + h) * 128 + k] = f2bf(d1);
    } else if (i < 128 * 128 + 64 * 128 + 128 * 8 + 128) {
        int k = i - (128 * 128 + 64 * 128 + 128 * 8);
        float s = 0.f, d = 0.f;
        #pragma unroll
        for (int dd = 0; dd < 64; dd++) {
            float w = W2[k * 64 + dd];
            s += w * as2[dd];
            d += w * ad2[dd];
        }
        Wt2[64 * 128 + k] = f2bf(s);
        Wt2[65 * 128 + k] = f2bf(d);
        #pragma unroll
        for (int r = 66; r < 80; r++) Wt2[r * 128 + k] = 0;
    }
}

constexpr int SC = 2048;

__global__ __launch_bounds__(256) void k_scan1(const int* __restrict__ deg, int N,
                                               int* __restrict__ partial) {
    int base = blockIdx.x * SC;
    int t = threadIdx.x;
    int s = 0;
    #pragma unroll
    for (int p = 0; p < SC / 256; p++) {
        int i = base + t + p * 256;
        if (i < N) s += deg[i];
    }
    #pragma unroll
    for (int off = 32; off; off >>= 1) s += __shfl_xor(s, off, 64);
    __shared__ int ws[4];
    int lane = t & 63, wid = t >> 6;
    if (lane == 0) ws[wid] = s;
    __syncthreads();
    if (t == 0) partial[blockIdx.x] = ws[0] + ws[1] + ws[2] + ws[3];
}

__global__ __launch_bounds__(256) void k_scan2(int* __restrict__ partial, int nb) {
    int t = threadIdx.x;
    int v = (t < nb) ? partial[t] : 0;
    int lane = t & 63, wid = t >> 6;
    int x = v;
    #pragma unroll
    for (int off = 1; off < 64; off <<= 1) {
        int y = __shfl_up(x, off, 64);
        if (lane >= off) x += y;
    }
    __shared__ int wsum[4];
    if (lane == 63) wsum[wid] = x;
    __syncthreads();
    int add = 0;
    for (int i = 0; i < wid; i++) add += wsum[i];
    if (t < nb) partial[t] = x + add - v;
}

__global__ __launch_bounds__(256) void k_scan3(const int* __restrict__ deg, int N, int Etot,
                                               const int* __restrict__ partial,
                                               int* __restrict__ rowptr,
                                               int* __restrict__ cursor) {
    int base = blockIdx.x * SC;
    int t = threadIdx.x;
    int i0 = base + t * 8;
    int v[8];
    int s = 0;
    #pragma unroll
    for (int p = 0; p < 8; p++) {
        int i = i0 + p;
        v[p] = (i < N) ? deg[i] : 0;
        s += v[p];
    }
    int lane = t & 63, wid = t >> 6;
    int x = s;
    #pragma unroll
    for (int off = 1; off < 64; off <<= 1) {
        int y = __shfl_up(x, off, 64);
        if (lane >= off) x += y;
    }
    __shared__ int wsum[4];
    if (lane == 63) wsum[wid] = x;
    __syncthreads();
    int add = 0;
    for (int i = 0; i < wid; i++) add += wsum[i];
    int excl = x - s + add + partial[blockIdx.x];
    #pragma unroll
    for (int p = 0; p < 8; p++) {
        int i = i0 + p;
        if (i < N) { rowptr[i] = excl; cursor[i] = excl; }
        excl += v[p];
    }
    if (blockIdx.x == 0 && t == 0) rowptr[N] = Etot;
}

// Scatter: col only (dstarr eliminated — dst is implicit in CSR grouping).

__global__ void k_fill(const int* __restrict__ srcE, const int* __restrict__ dstE,
                       int E, int N, int* __restrict__ cursor, int* __restrict__ col) {
    int i = blockIdx.x * blockDim.x + threadIdx.x;
    if (i < E) {
        int d = dstE[i];
        int p = atomicAdd(&cursor[d], 1);
        col[p] = srcE[i];
    } else if (i < E + N) {
        int d = i - E;
        int p = atomicAdd(&cursor[d], 1);
        col[p] = d;
    }
}

// ---------------- MFMA bf16 GEMM + fused BN-apply; logits via augmented columns -------
// HASBN: X is bf16 'agg'; y = relu(X*scale+shift)+Xres. RESBF16: Xres is bf16.
// WRITEX: store y (bf16) to Xout.

template <int DOUT, bool HASBN, bool RESBF16, bool WRITEX>
__global__ __launch_bounds__(256) void k_gemm(const void* __restrict__ Xv,
                                              const short* __restrict__ Wt,
                                              short* __restrict__ Hout,
                                              const float2* __restrict__ ss,
                                              const void* __restrict__ Xresv,
                                              short* __restrict__ Xout,
                                              float* __restrict__ als,
                                              float* __restrict__ ald, int Nrows) {
    constexpr int KP = 136;
    constexpr int CT = DOUT / 16;
    constexpr int CTT = CT + 1;
    __shared__ __align__(16) short Xs[128 * KP];
    __shared__ __align__(16) short Ws[(DOUT + 16) * KP];

    const int tid = threadIdx.x;
    const int row0 = blockIdx.x * 128;

    {
        int c4 = tid & 31;
        int r0 = tid >> 5;
        float2 ssv[4];
        if (HASBN) {
            #pragma unroll
            for (int j = 0; j < 4; j++) ssv[j] = ss[c4 * 4 + j];
        }
        #pragma unroll
        for (int p = 0; p < 16; p++) {
            int r = r0 + p * 8;
            int grow = row0 + r;
            float vp[4] = {0.f, 0.f, 0.f, 0.f};
            if (grow < Nrows) {
                if (HASBN) {
                    short4 xb = *(const short4*)&((const short*)Xv)[(size_t)grow * 128 + c4 * 4];
                    vp[0] = bf2f((unsigned short)xb.x);
                    vp[1] = bf2f((unsigned short)xb.y);
                    vp[2] = bf2f((unsigned short)xb.z);
                    vp[3] = bf2f((unsigned short)xb.w);
                    float xr[4];
                    if (RESBF16) {
                        short4 rb = *(const short4*)&((const short*)Xresv)[(size_t)grow * 128 + c4 * 4];
                        xr[0] = bf2f((unsigned short)rb.x);
                        xr[1] = bf2f((unsigned short)rb.y);
                        xr[2] = bf2f((unsigned short)rb.z);
                        xr[3] = bf2f((unsigned short)rb.w);
                    } else {
                        float4 rf = *(const float4*)&((const float*)Xresv)[(size_t)grow * 128 + c4 * 4];
                        xr[0] = rf.x; xr[1] = rf.y; xr[2] = rf.z; xr[3] = rf.w;
                    }
                    #pragma unroll
                    for (int j = 0; j < 4; j++)
                        vp[j] = fmaxf(vp[j] * ssv[j].x + ssv[j].y, 0.f) + xr[j];
                } else {
                    float4 v = *(const float4*)&((const float*)Xv)[(size_t)grow * 128 + c4 * 4];
                    vp[0] = v.x; vp[1] = v.y; vp[2] = v.z; vp[3] = v.w;
                }
            }
            short4 b;
            b.x = f2bf(vp[0]); b.y = f2bf(vp[1]); b.z = f2bf(vp[2]); b.w = f2bf(vp[3]);
            if (WRITEX && grow < Nrows)
                *(short4*)&Xout[(size_t)grow * 128 + c4 * 4] = b;
            *(short4*)&Xs[r * KP + c4 * 4] = b;
        }
    }
    {
        constexpr int UNITS = (DOUT + 16) * 16;
        #pragma unroll
        for (int p = 0; p < UNITS / 256; p++) {
            int u = tid + p * 256;
            int n = u >> 4;
            int kc = (u & 15) * 8;
            bf16x8 v = *(const bf16x8*)&Wt[n * 128 + kc];
            *(bf16x8*)&Ws[n * KP + kc] = v;
        }
    }
    __syncthreads();

    const int lane = tid & 63;
    const int wv = tid >> 6;
    const int m0 = wv * 32;
    const int ln = lane & 15;
    const int quad = lane >> 4;

    floatx4 acc[2][CTT];
    #pragma unroll
    for (int mt = 0; mt < 2; mt++)
        #pragma unroll
        for (int ct = 0; ct < CTT; ct++) acc[mt][ct] = (floatx4){0.f, 0.f, 0.f, 0.f};

    #pragma unroll
    for (int ks = 0; ks < 4; ks++) {
        int ko = ks * 32 + quad * 8;
        bf16x8 a0 = *(const bf16x8*)&Xs[(m0 + ln) * KP + ko];
        bf16x8 a1 = *(const bf16x8*)&Xs[(m0 + 16 + ln) * KP + ko];
        #pragma unroll
        for (int ct = 0; ct < CTT; ct++) {
            bf16x8 b = *(const bf16x8*)&Ws[(ct * 16 + ln) * KP + ko];
            acc[0][ct] = __builtin_amdgcn_mfma_f32_16x16x32_bf16(a0, b, acc[0][ct], 0, 0, 0);
            acc[1][ct] = __builtin_amdgcn_mfma_f32_16x16x32_bf16(a1, b, acc[1][ct], 0, 0, 0);
        }
    }

    #pragma unroll
    for (int mt = 0; mt < 2; mt++) {
        #pragma unroll
        for (int r = 0; r < 4; r++) {
            int grow = row0 + m0 + mt * 16 + quad * 4 + r;
            if (grow < Nrows) {
                #pragma unroll
                for (int ct = 0; ct < CT; ct++)
                    Hout[(size_t)grow * DOUT + ct * 16 + ln] = f2bf(acc[mt][ct][r]);
                float aug = acc[mt][CT][r];
                if (DOUT == 128) {
                    if (ln < 8) als[grow * 8 + ln] = aug;
                    else        ald[grow * 8 + (ln - 8)] = aug;
                } else {
                    if (ln == 0) als[grow] = aug;
                    else if (ln == 1) ald[grow] = aug;
                }
            }
        }
    }
}

// ---------------- aggregate: 1 node per wave, scalarized indices + fused BN stats ------
// col chunk loaded once per 64 edges into one VGPR; per-edge index via v_readlane (SGPR)
// -> SALU address math for als/H gathers; uniform loop bounds -> zero divergence.

__global__ __launch_bounds__(256) void k_agg(const int* __restrict__ rowptr,
                                             const int* __restrict__ col,
                                             const short* __restrict__ Hb,
                                             const float* __restrict__ als,
                                             const float* __restrict__ ald,
                                             const float* __restrict__ bias,
                                             short* __restrict__ out,
                                             float* __restrict__ part, int N) {
    __shared__ float red[4][128];
    const int wv = threadIdx.x >> 6;
    const int lane = threadIdx.x & 63;
    const int node = blockIdx.x * 4 + wv;
    const int h = lane >> 3;
    const int* Hi = (const int*)Hb;
    float o0 = 0.f, o1 = 0.f;

    if (node < N) {
        int j = __builtin_amdgcn_readfirstlane(rowptr[node]);
        const int end = __builtin_amdgcn_readfirstlane(rowptr[node + 1]);
        const float aldv = ald[node * 8 + h];
        float s = 0.f, a0 = 0.f, a1 = 0.f;

        while (j < end) {
            int navail = end - j;
            if (navail > 64) navail = 64;
            int cidx = j + lane;
            if (cidx > end - 1) cidx = end - 1;
            int cbuf = col[cidx];
            int k = 0;
            for (; k + 4 <= navail; k += 4) {
                int c0 = __builtin_amdgcn_readlane(cbuf, k);
                int c1 = __builtin_amdgcn_readlane(cbuf, k + 1);
                int c2 = __builtin_amdgcn_readlane(cbuf, k + 2);
                int c3 = __builtin_amdgcn_readlane(cbuf, k + 3);
                const float* q0 = als + c0 * 8;
                const float* q1 = als + c1 * 8;
                const float* q2 = als + c2 * 8;
                const float* q3 = als + c3 * 8;
                const int* r0 = Hi + (c0 << 6);
                const int* r1 = Hi + (c1 << 6);
                const int* r2 = Hi + (c2 << 6);
                const int* r3 = Hi + (c3 << 6);
                float w0 = q0[h], w1 = q1[h], w2 = q2[h], w3 = q3[h];
                int p0 = r0[lane], p1 = r1[lane], p2 = r2[lane], p3 = r3[lane];
                float e;
                e = w0 + aldv; e = LRELU(e); float x0 = __expf(e);
                e = w1 + aldv; e = LRELU(e); float x1 = __expf(e);
                e = w2 + aldv; e = LRELU(e); float x2 = __expf(e);
                e = w3 + aldv; e = LRELU(e); float x3 = __expf(e);
                s += x0; a0 += x0 * bflo(p0); a1 += x0 * bfhi(p0);
                s += x1; a0 += x1 * bflo(p1); a1 += x1 * bfhi(p1);
                s += x2; a0 += x2 * bflo(p2); a1 += x2 * bfhi(p2);
                s += x3; a0 += x3 * bflo(p3); a1 += x3 * bfhi(p3);
            }
            for (; k < navail; k++) {
                int c = __builtin_amdgcn_readlane(cbuf, k);
                const float* q = als + c * 8;
                const int* r = Hi + (c << 6);
                float w = q[h];
                int p = r[lane];
                float e = w + aldv; e = LRELU(e); float x = __expf(e);
                s += x; a0 += x * bflo(p); a1 += x * bfhi(p);
            }
            j += navail;
        }

        float2 bv = ((const float2*)bias)[lane];
        float inv = 1.f / (s + 1e-16f);
        o0 = a0 * inv + bv.x;
        o1 = a1 * inv + bv.y;
        int pack = (unsigned short)f2bf(o0) | ((unsigned)(unsigned short)f2bf(o1) << 16);
        ((int*)out)[(size_t)node * 64 + lane] = pack;
    }

    red[wv][2 * lane] = o0;
    red[wv][2 * lane + 1] = o1;
    __syncthreads();
    if (threadIdx.x < 128) {
        int c = threadIdx.x;
        float s = 0.f, q = 0.f;
        #pragma unroll
        for (int r = 0; r < 4; r++) {
            float v = red[r][c];
            s += v;
            q += v * v;
        }
        float* slot = part + (blockIdx.x & 63) * 256;
        atomicAdd(&slot[c], s);
        atomicAdd(&slot[128 + c], q);
    }
}

// ---------------- reduce partials -> (scale, shift); re-zero part ----------------

__global__ __launch_bounds__(128) void k_bnreduce(float* __restrict__ part,
                                                  const float* __restrict__ g,
                                                  const float* __restrict__ bt,
                                                  float invN, float2* __restrict__ ss) {
    int c = threadIdx.x;
    float s = 0.f, q = 0.f;
    #pragma unroll
    for (int k = 0; k < 64; k++) {
        s += part[k * 256 + c];
        q += part[k * 256 + 128 + c];
    }
    #pragma unroll
    for (int k = 0; k < 64; k++) {
        part[k * 256 + c] = 0.f;
        part[k * 256 + 128 + c] = 0.f;
    }
    float mu = s * invN;
    float var = q * invN - mu * mu;
    float scale = rsqrtf(var + 1e-5f) * g[c];
    ss[c] = make_float2(scale, bt[c] - mu * scale);
}

// ---------------- layer-2: 1 node per wave + fused edge weights + LayerNorm ----------

__global__ __launch_bounds__(256) void k_agg2ln(const int* __restrict__ rowptr,
                                                const int* __restrict__ col,
                                                const short* __restrict__ Hb2,
                                                const float* __restrict__ als,
                                                const float* __restrict__ ald,
                                                const float* __restrict__ b2,
                                                const float* __restrict__ lng,
                                                const float* __restrict__ lnb,
                                                float* __restrict__ out, int N) {
    const int wv = threadIdx.x >> 6;
    const int lane = threadIdx.x & 63;
    const int node = blockIdx.x * 4 + wv;
    const unsigned short* H = (const unsigned short*)Hb2;
    if (node >= N) return;

    int j = __builtin_amdgcn_readfirstlane(rowptr[node]);
    const int end = __builtin_amdgcn_readfirstlane(rowptr[node + 1]);
    const float aldv = ald[node];
    float s = 0.f, a = 0.f;

    while (j < end) {
        int navail = end - j;
        if (navail > 64) navail = 64;
        int cidx = j + lane;
        if (cidx > end - 1) cidx = end - 1;
        int cbuf = col[cidx];
        int k = 0;
        for (; k + 4 <= navail; k += 4) {
            int c0 = __builtin_amdgcn_readlane(cbuf, k);
            int c1 = __builtin_amdgcn_readlane(cbuf, k + 1);
            int c2 = __builtin_amdgcn_readlane(cbuf, k + 2);
            int c3 = __builtin_amdgcn_readlane(cbuf, k + 3);
            const unsigned short* r0 = H + (c0 << 6);
            const unsigned short* r1 = H + (c1 << 6);
            const unsigned short* r2 = H + (c2 << 6);
            const unsigned short* r3 = H + (c3 << 6);
            float w0 = als[c0], w1 = als[c1], w2 = als[c2], w3 = als[c3];
            unsigned short p0 = r0[lane], p1 = r1[lane], p2 = r2[lane], p3 = r3[lane];
            float e;
            e = w0 + aldv; e = LRELU(e); float x0 = __expf(e);
            e = w1 + aldv; e = LRELU(e); float x1 = __expf(e);
            e = w2 + aldv; e = LRELU(e); float x2 = __expf(e);
            e = w3 + aldv; e = LRELU(e); float x3 = __expf(e);
            s += x0; a += x0 * bf2f(p0);
            s += x1; a += x1 * bf2f(p1);
            s += x2; a += x2 * bf2f(p2);
            s += x3; a += x3 * bf2f(p3);
        }
        for (; k < navail; k++) {
            int c = __builtin_amdgcn_readlane(cbuf, k);
            float w = als[c];
            unsigned short p = H[(c << 6) + lane];
            float e = w + aldv; e = LRELU(e); float x = __expf(e);
            s += x; a += x * bf2f(p);
        }
        j += navail;
    }

    float v = a / (s + 1e-16f) + b2[lane];
    float su = v, sq = v * v;
    #pragma unroll
    for (int off = 32; off; off >>= 1) {
        su += __shfl_xor(su, off, 64);
        sq += __shfl_xor(sq, off, 64);
    }
    float mu = su * (1.f / 64.f);
    float var = sq * (1.f / 64.f) - mu * mu;
    float r = rsqrtf(var + 1e-5f);
    out[(size_t)node * 64 + lane] = (v - mu) * r * lng[lane] + lnb[lane];
}

// ---------------- launch ----------------

extern "C" void kernel_launch(void* const* d_in, const int* in_sizes, int n_in,
                              void* d_out, int out_size, void* d_ws, size_t ws_size,
                              hipStream_t stream) {
    const float* x   = (const float*)d_in[0];
    const int*   ei  = (const int*)d_in[1];
    const float* W0  = (const float*)d_in[2];
    const float* as0 = (const float*)d_in[3];
    const float* ad0 = (const float*)d_in[4];
    const float* b0  = (const float*)d_in[5];
    const float* g0  = (const float*)d_in[6];
    const float* bt0 = (const float*)d_in[7];
    const float* W1  = (const float*)d_in[8];
    const float* as1 = (const float*)d_in[9];
    const float* ad1 = (const float*)d_in[10];
    const float* b1  = (const float*)d_in[11];
    const float* g1  = (const float*)d_in[12];
    const float* bt1 = (const float*)d_in[13];
    const float* W2  = (const float*)d_in[14];
    const float* as2 = (const float*)d_in[15];
    const float* ad2 = (const float*)d_in[16];
    const float* b2  = (const float*)d_in[17];
    const float* lng = (const float*)d_in[18];
    const float* lnb = (const float*)d_in[19];

    const int N = in_sizes[0] / 128;
    const int E = in_sizes[1] / 2;
    const int Etot = E + N;

    char* p = (char*)d_ws;
    auto carve = [&](size_t bytes) {
        void* q = (void*)p;
        p += (bytes + 255) & ~(size_t)255;
        return q;
    };
    short* Hb     = (short*)carve((size_t)N * 128 * 2);
    short* aggb   = (short*)carve((size_t)N * 128 * 2);
    short* x1b    = (short*)carve((size_t)N * 128 * 2);
    float* als    = (float*)carve((size_t)N * 8 * 4);
    float* ald    = (float*)carve((size_t)N * 8 * 4);
    int*   rowptr = (int*)carve((size_t)(N + 1) * 4);
    int*   cursor = (int*)carve((size_t)(N + 1) * 4);
    // deg + part adjacent -> one memset
    const size_t degpad = ((size_t)N * 4 + 255) & ~(size_t)255;
    int*   deg    = (int*)carve(degpad);
    float* part   = (float*)carve(64 * 256 * 4);
    int*   col    = (int*)carve((size_t)Etot * 4);
    float2* ss    = (float2*)carve(128 * 8);
    short* Wt0    = (short*)carve(144 * 128 * 2);
    short* Wt1    = (short*)carve(144 * 128 * 2);
    short* Wt2    = (short*)carve(80 * 128 * 2);
    int*   partial= (int*)carve(256 * 4);

    const float invN = 1.f / (float)N;
    const int eb = (E + N + 255) / 256;
    const int nsb = (N + SC - 1) / SC;

    hipMemsetAsync(deg, 0, degpad + 64 * 256 * 4, stream);
    k_count_wprep<<<eb, 256, 0, stream>>>(ei + E, E, N, deg, W0, W1, W2,
                                          as0, ad0, as1, ad1, as2, ad2, Wt0, Wt1, Wt2);
    k_scan1<<<nsb, 256, 0, stream>>>(deg, N, partial);
    k_scan2<<<1, 256, 0, stream>>>(partial, nsb);
    k_scan3<<<nsb, 256, 0, stream>>>(deg, N, Etot, partial, rowptr, cursor);
    k_fill<<<eb, 256, 0, stream>>>(ei, ei + E, E, N, cursor, col);

    const int gb = (N + 127) / 128;
    const int ab = (N + 3) / 4;

    // ---- layer 0 ----
    k_gemm<128, false, false, false><<<gb, 256, 0, stream>>>(x, Wt0, Hb, nullptr, nullptr,
                                                             nullptr, als, ald, N);
    k_agg<<<ab, 256, 0, stream>>>(rowptr, col, Hb, als, ald, b0, aggb, part, N);
    k_bnreduce<<<1, 128, 0, stream>>>(part, g0, bt0, invN, ss);

    // ---- layer 1 (BN-apply fused into GEMM staging; agg/x1 bf16) ----
    k_gemm<128, true, false, true><<<gb, 256, 0, stream>>>(aggb, Wt1, Hb, ss, x, x1b,
                                                           als, ald, N);
    k_agg<<<ab, 256, 0, stream>>>(rowptr, col, Hb, als, ald, b1, aggb, part, N);
    k_bnreduce<<<1, 128, 0, stream>>>(part, g1, bt1, invN, ss);

    // ---- layer 2 (BN-apply fused; bf16 residual; x2 never materialized) ----
    k_gemm<64, true, true, false><<<gb, 256, 0, stream>>>(aggb, Wt2, Hb, ss, x1b, nullptr,
                                                          als, ald, N);
    k_agg2ln<<<ab, 256, 0, stream>>>(rowptr, col, Hb, als, ald, b2, lng, lnb,
                                     (float*)d_out, N);
}

// Round 3
// 428.878 us; speedup vs baseline: 1.1181x; 1.1181x over previous
//
#include <hip/hip_runtime.h>
#include <hip/hip_bf16.h>

#define LRELU(e) ((e) > 0.f ? (e) : 0.2f * (e))

typedef __attribute__((ext_vector_type(8))) short bf16x8;
typedef __attribute__((ext_vector_type(4))) float floatx4;

__device__ inline short f2bf(float f) {
    union { float f; unsigned u; } v; v.f = f;
    unsigned r = v.u + 0x7fffu + ((v.u >> 16) & 1u);
    return (short)(r >> 16);
}
__device__ inline float bflo(int p) {
    union { unsigned u; float f; } v; v.u = (unsigned)p << 16; return v.f;
}
__device__ inline float bfhi(int p) {
    union { unsigned u; float f; } v; v.u = (unsigned)p & 0xffff0000u; return v.f;
}
__device__ inline float bf2f(unsigned short s) {
    union { unsigned u; float f; } v; v.u = (unsigned)s << 16; return v.f;
}

// ---------------- CSR build + weight prep (incl. folded attention columns) ----------

__global__ void k_count_wprep(const int* __restrict__ dstE, int E, int N,
                              int* __restrict__ deg,
                              const float* __restrict__ W0, const float* __restrict__ W1,
                              const float* __restrict__ W2,
                              const float* __restrict__ as0, const float* __restrict__ ad0,
                              const float* __restrict__ as1, const float* __restrict__ ad1,
                              const float* __restrict__ as2, const float* __restrict__ ad2,
                              short* __restrict__ Wt0, short* __restrict__ Wt1,
                              short* __restrict__ Wt2) {
    int i = blockIdx.x * blockDim.x + threadIdx.x;
    if (i < E) atomicAdd(&deg[dstE[i]], 1);
    else if (i < E + N) atomicAdd(&deg[i - E], 1);

    if (i < 128 * 128) {
        int n = i >> 7, k = i & 127;
        Wt0[n * 128 + k] = f2bf(W0[k * 128 + n]);
        Wt1[n * 128 + k] = f2bf(W1[k * 128 + n]);
    } else if (i < 128 * 128 + 64 * 128) {
        int j = i - 128 * 128;
        int n = j >> 7, k = j & 127;
        Wt2[n * 128 + k] = f2bf(W2[k * 64 + n]);
    } else if (i < 128 * 128 + 64 * 128 + 128 * 8) {
        int j = i - (128 * 128 + 64 * 128);
        int k = j >> 3, h = j & 7;
        float s0 = 0.f, d0 = 0.f, s1 = 0.f, d1 = 0.f;
        #pragma unroll
        for (int d = 0; d < 16; d++) {
            float w0 = W0[k * 128 + h * 16 + d];
            float w1 = W1[k * 128 + h * 16 + d];
            s0 += w0 * as0[h * 16 + d];
            d0 += w0 * ad0[h * 16 + d];
            s1 += w1 * as1[h * 16 + d];
            d1 += w1 * ad1[h * 16 + d];
        }
        Wt0[(128 + h) * 128 + k] = f2bf(s0);
        Wt0[(136 + h) * 128 + k] = f2bf(d0);
        Wt1[(128 + h) * 128 + k] = f2bf(s1);
        Wt1[(136 + h) * 128 + k] = f2bf(d1);
    } else if (i < 128 * 128 + 64 * 128 + 128 * 8 + 128) {
        int k = i - (128 * 128 + 64 * 128 + 128 * 8);
        float s = 0.f, d = 0.f;
        #pragma unroll
        for (int dd = 0; dd < 64; dd++) {
            float w = W2[k * 64 + dd];
            s += w * as2[dd];
            d += w * ad2[dd];
        }
        Wt2[64 * 128 + k] = f2bf(s);
        Wt2[65 * 128 + k] = f2bf(d);
        #pragma unroll
        for (int r = 66; r < 80; r++) Wt2[r * 128 + k] = 0;
    }
}

constexpr int SC = 2048;

__global__ __launch_bounds__(256) void k_scan1(const int* __restrict__ deg, int N,
                                               int* __restrict__ partial) {
    int base = blockIdx.x * SC;
    int t = threadIdx.x;
    int s = 0;
    #pragma unroll
    for (int p = 0; p < SC / 256; p++) {
        int i = base + t + p * 256;
        if (i < N) s += deg[i];
    }
    #pragma unroll
    for (int off = 32; off; off >>= 1) s += __shfl_xor(s, off, 64);
    __shared__ int ws[4];
    int lane = t & 63, wid = t >> 6;
    if (lane == 0) ws[wid] = s;
    __syncthreads();
    if (t == 0) partial[blockIdx.x] = ws[0] + ws[1] + ws[2] + ws[3];
}

__global__ __launch_bounds__(256) void k_scan2(int* __restrict__ partial, int nb) {
    int t = threadIdx.x;
    int v = (t < nb) ? partial[t] : 0;
    int lane = t & 63, wid = t >> 6;
    int x = v;
    #pragma unroll
    for (int off = 1; off < 64; off <<= 1) {
        int y = __shfl_up(x, off, 64);
        if (lane >= off) x += y;
    }
    __shared__ int wsum[4];
    if (lane == 63) wsum[wid] = x;
    __syncthreads();
    int add = 0;
    for (int i = 0; i < wid; i++) add += wsum[i];
    if (t < nb) partial[t] = x + add - v;
}

// rowptr scan; also emits per-bucket (128-node) binned-edge base cursors:
// bcursor[b] = rowptr[128b] - 128b  (each node has exactly 1 self loop).

__global__ __launch_bounds__(256) void k_scan3(const int* __restrict__ deg, int N, int Etot,
                                               const int* __restrict__ partial,
                                               int* __restrict__ rowptr,
                                               int* __restrict__ bcursor) {
    int base = blockIdx.x * SC;
    int t = threadIdx.x;
    int i0 = base + t * 8;
    int v[8];
    int s = 0;
    #pragma unroll
    for (int p = 0; p < 8; p++) {
        int i = i0 + p;
        v[p] = (i < N) ? deg[i] : 0;
        s += v[p];
    }
    int lane = t & 63, wid = t >> 6;
    int x = s;
    #pragma unroll
    for (int off = 1; off < 64; off <<= 1) {
        int y = __shfl_up(x, off, 64);
        if (lane >= off) x += y;
    }
    __shared__ int wsum[4];
    if (lane == 63) wsum[wid] = x;
    __syncthreads();
    int add = 0;
    for (int i = 0; i < wid; i++) add += wsum[i];
    int excl = x - s + add + partial[blockIdx.x];
    #pragma unroll
    for (int p = 0; p < 8; p++) {
        int i = i0 + p;
        if (i < N) {
            rowptr[i] = excl;
            if ((i & 127) == 0) bcursor[i >> 7] = excl - i;
        }
        excl += v[p];
    }
    if (blockIdx.x == 0 && t == 0) rowptr[N] = Etot;
}

// ---------------- binned edge scatter (pass B): block-local multisplit ----------------
// Buckets of 128 dst nodes (shift 7); nb = ceil(N/128) must be <= 1024 (N <= 131072).

constexpr int EPT = 16;

__global__ __launch_bounds__(256) void k_bin(const int* __restrict__ srcE,
                                             const int* __restrict__ dstE, int E, int nb,
                                             int* __restrict__ bcursor,
                                             int2* __restrict__ ebin) {
    __shared__ int cnt[1024];
    __shared__ int base[1024];
    for (int b = threadIdx.x; b < nb; b += 256) cnt[b] = 0;
    __syncthreads();
    int i0 = blockIdx.x * (256 * EPT) + threadIdx.x;
    int rb[EPT];
    #pragma unroll
    for (int k = 0; k < EPT; k++) {
        int i = i0 + k * 256;
        if (i < E) {
            int b = dstE[i] >> 7;
            rb[k] = (atomicAdd(&cnt[b], 1) << 10) | b;   // rank(12b) | bucket(10b)
        } else {
            rb[k] = -1;
        }
    }
    __syncthreads();
    for (int b = threadIdx.x; b < nb; b += 256) {
        int c = cnt[b];
        base[b] = c ? atomicAdd(&bcursor[b], c) : 0;
    }
    __syncthreads();
    #pragma unroll
    for (int k = 0; k < EPT; k++) {
        int i = i0 + k * 256;
        if (i < E) {
            int v = rb[k];
            int b = v & 1023;
            int r = v >> 10;
            ebin[base[b] + r] = make_int2(srcE[i], dstE[i]);   // re-read: L1/L2 hot
        }
    }
}

// ---------------- CSR fill (pass C): one block per bucket, LDS cursors -----------------

__global__ __launch_bounds__(256) void k_cfill(const int* __restrict__ rowptr,
                                               const int2* __restrict__ ebin,
                                               int* __restrict__ col, int N) {
    int n0 = blockIdx.x << 7;
    int nn = N - n0; if (nn > 128) nn = 128;
    __shared__ int cur[128];
    __shared__ int eb[2];
    int t = threadIdx.x;
    if (t <= nn) {
        int rp = rowptr[n0 + t];
        if (t < nn) {
            col[rp] = n0 + t;          // self loop in first slot of its row
            cur[t] = rp + 1;
        }
        if (t == 0) eb[0] = rp - n0;
        if (t == nn) eb[1] = rp - (n0 + nn);
    }
    __syncthreads();
    int ebase = eb[0];
    int ecnt = eb[1] - ebase;
    for (int i = t; i < ecnt; i += 256) {
        int2 e = ebin[ebase + i];
        int p = atomicAdd(&cur[e.y - n0], 1);
        col[p] = e.x;
    }
}

// ---------------- MFMA bf16 GEMM + fused BN-apply; logits via augmented columns -------
// HASBN: X is bf16 'agg'; y = relu(X*scale+shift)+Xres. RESBF16: Xres is bf16.
// WRITEX: store y (bf16) to Xout.

template <int DOUT, bool HASBN, bool RESBF16, bool WRITEX>
__global__ __launch_bounds__(256) void k_gemm(const void* __restrict__ Xv,
                                              const short* __restrict__ Wt,
                                              short* __restrict__ Hout,
                                              const float2* __restrict__ ss,
                                              const void* __restrict__ Xresv,
                                              short* __restrict__ Xout,
                                              float* __restrict__ als,
                                              float* __restrict__ ald, int Nrows) {
    constexpr int KP = 136;
    constexpr int CT = DOUT / 16;
    constexpr int CTT = CT + 1;
    __shared__ __align__(16) short Xs[128 * KP];
    __shared__ __align__(16) short Ws[(DOUT + 16) * KP];

    const int tid = threadIdx.x;
    const int row0 = blockIdx.x * 128;

    {
        int c4 = tid & 31;
        int r0 = tid >> 5;
        float2 ssv[4];
        if (HASBN) {
            #pragma unroll
            for (int j = 0; j < 4; j++) ssv[j] = ss[c4 * 4 + j];
        }
        #pragma unroll
        for (int p = 0; p < 16; p++) {
            int r = r0 + p * 8;
            int grow = row0 + r;
            float vp[4] = {0.f, 0.f, 0.f, 0.f};
            if (grow < Nrows) {
                if (HASBN) {
                    short4 xb = *(const short4*)&((const short*)Xv)[(size_t)grow * 128 + c4 * 4];
                    vp[0] = bf2f((unsigned short)xb.x);
                    vp[1] = bf2f((unsigned short)xb.y);
                    vp[2] = bf2f((unsigned short)xb.z);
                    vp[3] = bf2f((unsigned short)xb.w);
                    float xr[4];
                    if (RESBF16) {
                        short4 rb = *(const short4*)&((const short*)Xresv)[(size_t)grow * 128 + c4 * 4];
                        xr[0] = bf2f((unsigned short)rb.x);
                        xr[1] = bf2f((unsigned short)rb.y);
                        xr[2] = bf2f((unsigned short)rb.z);
                        xr[3] = bf2f((unsigned short)rb.w);
                    } else {
                        float4 rf = *(const float4*)&((const float*)Xresv)[(size_t)grow * 128 + c4 * 4];
                        xr[0] = rf.x; xr[1] = rf.y; xr[2] = rf.z; xr[3] = rf.w;
                    }
                    #pragma unroll
                    for (int j = 0; j < 4; j++)
                        vp[j] = fmaxf(vp[j] * ssv[j].x + ssv[j].y, 0.f) + xr[j];
                } else {
                    float4 v = *(const float4*)&((const float*)Xv)[(size_t)grow * 128 + c4 * 4];
                    vp[0] = v.x; vp[1] = v.y; vp[2] = v.z; vp[3] = v.w;
                }
            }
            short4 b;
            b.x = f2bf(vp[0]); b.y = f2bf(vp[1]); b.z = f2bf(vp[2]); b.w = f2bf(vp[3]);
            if (WRITEX && grow < Nrows)
                *(short4*)&Xout[(size_t)grow * 128 + c4 * 4] = b;
            *(short4*)&Xs[r * KP + c4 * 4] = b;
        }
    }
    {
        constexpr int UNITS = (DOUT + 16) * 16;
        #pragma unroll
        for (int p = 0; p < UNITS / 256; p++) {
            int u = tid + p * 256;
            int n = u >> 4;
            int kc = (u & 15) * 8;
            bf16x8 v = *(const bf16x8*)&Wt[n * 128 + kc];
            *(bf16x8*)&Ws[n * KP + kc] = v;
        }
    }
    __syncthreads();

    const int lane = tid & 63;
    const int wv = tid >> 6;
    const int m0 = wv * 32;
    const int ln = lane & 15;
    const int quad = lane >> 4;

    floatx4 acc[2][CTT];
    #pragma unroll
    for (int mt = 0; mt < 2; mt++)
        #pragma unroll
        for (int ct = 0; ct < CTT; ct++) acc[mt][ct] = (floatx4){0.f, 0.f, 0.f, 0.f};

    #pragma unroll
    for (int ks = 0; ks < 4; ks++) {
        int ko = ks * 32 + quad * 8;
        bf16x8 a0 = *(const bf16x8*)&Xs[(m0 + ln) * KP + ko];
        bf16x8 a1 = *(const bf16x8*)&Xs[(m0 + 16 + ln) * KP + ko];
        #pragma unroll
        for (int ct = 0; ct < CTT; ct++) {
            bf16x8 b = *(const bf16x8*)&Ws[(ct * 16 + ln) * KP + ko];
            acc[0][ct] = __builtin_amdgcn_mfma_f32_16x16x32_bf16(a0, b, acc[0][ct], 0, 0, 0);
            acc[1][ct] = __builtin_amdgcn_mfma_f32_16x16x32_bf16(a1, b, acc[1][ct], 0, 0, 0);
        }
    }

    #pragma unroll
    for (int mt = 0; mt < 2; mt++) {
        #pragma unroll
        for (int r = 0; r < 4; r++) {
            int grow = row0 + m0 + mt * 16 + quad * 4 + r;
            if (grow < Nrows) {
                #pragma unroll
                for (int ct = 0; ct < CT; ct++)
                    Hout[(size_t)grow * DOUT + ct * 16 + ln] = f2bf(acc[mt][ct][r]);
                float aug = acc[mt][CT][r];
                if (DOUT == 128) {
                    if (ln < 8) als[grow * 8 + ln] = aug;
                    else        ald[grow * 8 + (ln - 8)] = aug;
                } else {
                    if (ln == 0) als[grow] = aug;
                    else if (ln == 1) ald[grow] = aug;
                }
            }
        }
    }
}

// ---------------- aggregate: 2 nodes per wave + fused edge weights + BN stats ----------
// Edge weight computed in-loop: w = exp(lrelu(als[src,h] + ald[dst,h])).
// dst == the node this wave owns, so ald term is a per-wave register.

__global__ __launch_bounds__(256) void k_agg(const int* __restrict__ rowptr,
                                             const int* __restrict__ col,
                                             const short* __restrict__ Hb,
                                             const float* __restrict__ als,
                                             const float* __restrict__ ald,
                                             const float* __restrict__ bias,
                                             short* __restrict__ out,
                                             float* __restrict__ part, int N) {
    __shared__ float red[8][128];
    int wv = threadIdx.x >> 6;
    int lane = threadIdx.x & 63;
    int nodeA = blockIdx.x * 8 + wv * 2;
    int nodeB = nodeA + 1;
    int h = lane >> 3;
    const int* Hi = (const int*)Hb;
    bool vA = nodeA < N, vB = nodeB < N;
    int jA = 0, endA = 0, jB = 0, endB = 0;
    float aldA = 0.f, aldB = 0.f;
    if (vA) { jA = rowptr[nodeA]; endA = rowptr[nodeA + 1]; aldA = ald[nodeA * 8 + h]; }
    if (vB) { jB = rowptr[nodeB]; endB = rowptr[nodeB + 1]; aldB = ald[nodeB * 8 + h]; }
    float sA = 0.f, a0A = 0.f, a1A = 0.f;
    float sB = 0.f, a0B = 0.f, a1B = 0.f;

    while (jA + 4 <= endA && jB + 4 <= endB) {
        int c[8];
        #pragma unroll
        for (int k = 0; k < 4; k++) { c[k] = col[jA + k]; c[4 + k] = col[jB + k]; }
        float aw[8];
        int p[8];
        #pragma unroll
        for (int k = 0; k < 4; k++) {
            aw[k] = als[c[k] * 8 + h];
            aw[4 + k] = als[c[4 + k] * 8 + h];
            p[k] = Hi[(c[k] << 6) + lane];
            p[4 + k] = Hi[(c[4 + k] << 6) + lane];
        }
        #pragma unroll
        for (int k = 0; k < 4; k++) {
            float e = aw[k] + aldA; e = LRELU(e); float w = __expf(e);
            sA += w;  a0A += w * bflo(p[k]);  a1A += w * bfhi(p[k]);
            float e2 = aw[4 + k] + aldB; e2 = LRELU(e2); float w2 = __expf(e2);
            sB += w2; a0B += w2 * bflo(p[4 + k]); a1B += w2 * bfhi(p[4 + k]);
        }
        jA += 4; jB += 4;
    }
    for (; jA + 4 <= endA; jA += 4) {
        int c[4]; float aw[4]; int p[4];
        #pragma unroll
        for (int k = 0; k < 4; k++) c[k] = col[jA + k];
        #pragma unroll
        for (int k = 0; k < 4; k++) { aw[k] = als[c[k] * 8 + h]; p[k] = Hi[(c[k] << 6) + lane]; }
        #pragma unroll
        for (int k = 0; k < 4; k++) {
            float e = aw[k] + aldA; e = LRELU(e); float w = __expf(e);
            sA += w; a0A += w * bflo(p[k]); a1A += w * bfhi(p[k]);
        }
    }
    for (; jA < endA; jA++) {
        int cc = col[jA];
        float e = als[cc * 8 + h] + aldA; e = LRELU(e); float w = __expf(e);
        int pp = Hi[(cc << 6) + lane];
        sA += w; a0A += w * bflo(pp); a1A += w * bfhi(pp);
    }
    for (; jB + 4 <= endB; jB += 4) {
        int c[4]; float aw[4]; int p[4];
        #pragma unroll
        for (int k = 0; k < 4; k++) c[k] = col[jB + k];
        #pragma unroll
        for (int k = 0; k < 4; k++) { aw[k] = als[c[k] * 8 + h]; p[k] = Hi[(c[k] << 6) + lane]; }
        #pragma unroll
        for (int k = 0; k < 4; k++) {
            float e = aw[k] + aldB; e = LRELU(e); float w = __expf(e);
            sB += w; a0B += w * bflo(p[k]); a1B += w * bfhi(p[k]);
        }
    }
    for (; jB < endB; jB++) {
        int cc = col[jB];
        float e = als[cc * 8 + h] + aldB; e = LRELU(e); float w = __expf(e);
        int pp = Hi[(cc << 6) + lane];
        sB += w; a0B += w * bflo(pp); a1B += w * bfhi(pp);
    }

    float bx = bias[2 * lane], by = bias[2 * lane + 1];
    float2 oA = make_float2(0.f, 0.f), oB = make_float2(0.f, 0.f);
    if (vA) {
        float inv = 1.f / (sA + 1e-16f);
        oA.x = a0A * inv + bx;
        oA.y = a1A * inv + by;
        int pack = (unsigned short)f2bf(oA.x) | ((unsigned)(unsigned short)f2bf(oA.y) << 16);
        ((int*)out)[(size_t)nodeA * 64 + lane] = pack;
    }
    if (vB) {
        float inv = 1.f / (sB + 1e-16f);
        oB.x = a0B * inv + bx;
        oB.y = a1B * inv + by;
        int pack = (unsigned short)f2bf(oB.x) | ((unsigned)(unsigned short)f2bf(oB.y) << 16);
        ((int*)out)[(size_t)nodeB * 64 + lane] = pack;
    }
    red[wv * 2][2 * lane] = oA.x;
    red[wv * 2][2 * lane + 1] = oA.y;
    red[wv * 2 + 1][2 * lane] = oB.x;
    red[wv * 2 + 1][2 * lane + 1] = oB.y;
    __syncthreads();
    if (threadIdx.x < 128) {
        int c = threadIdx.x;
        float s = 0.f, q = 0.f;
        #pragma unroll
        for (int r = 0; r < 8; r++) {
            float v = red[r][c];
            s += v;
            q += v * v;
        }
        float* slot = part + (blockIdx.x & 63) * 256;
        atomicAdd(&slot[c], s);
        atomicAdd(&slot[128 + c], q);
    }
}

// ---------------- reduce partials -> (scale, shift); re-zero part ----------------

__global__ __launch_bounds__(128) void k_bnreduce(float* __restrict__ part,
                                                  const float* __restrict__ g,
                                                  const float* __restrict__ bt,
                                                  float invN, float2* __restrict__ ss) {
    int c = threadIdx.x;
    float s = 0.f, q = 0.f;
    #pragma unroll
    for (int k = 0; k < 64; k++) {
        s += part[k * 256 + c];
        q += part[k * 256 + 128 + c];
    }
    #pragma unroll
    for (int k = 0; k < 64; k++) {
        part[k * 256 + c] = 0.f;
        part[k * 256 + 128 + c] = 0.f;
    }
    float mu = s * invN;
    float var = q * invN - mu * mu;
    float scale = rsqrtf(var + 1e-5f) * g[c];
    ss[c] = make_float2(scale, bt[c] - mu * scale);
}

// ---------------- layer-2: 2 nodes per wave + fused edge weights + LayerNorm ----------

__global__ __launch_bounds__(256) void k_agg2ln(const int* __restrict__ rowptr,
                                                const int* __restrict__ col,
                                                const short* __restrict__ Hb2,
                                                const float* __restrict__ als,
                                                const float* __restrict__ ald,
                                                const float* __restrict__ b2,
                                                const float* __restrict__ lng,
                                                const float* __restrict__ lnb,
                                                float* __restrict__ out, int N) {
    int wv = threadIdx.x >> 6;
    int lane = threadIdx.x & 63;
    int nodeA = blockIdx.x * 8 + wv * 2;
    int nodeB = nodeA + 1;
    const unsigned short* H = (const unsigned short*)Hb2;
    bool vA = nodeA < N, vB = nodeB < N;
    int jA = 0, endA = 0, jB = 0, endB = 0;
    float aldA = 0.f, aldB = 0.f;
    if (vA) { jA = rowptr[nodeA]; endA = rowptr[nodeA + 1]; aldA = ald[nodeA]; }
    if (vB) { jB = rowptr[nodeB]; endB = rowptr[nodeB + 1]; aldB = ald[nodeB]; }
    float sA = 0.f, aA = 0.f, sB = 0.f, aB = 0.f;

    while (jA + 4 <= endA && jB + 4 <= endB) {
        int c[8];
        #pragma unroll
        for (int k = 0; k < 4; k++) { c[k] = col[jA + k]; c[4 + k] = col[jB + k]; }
        float aw[8];
        unsigned short p[8];
        #pragma unroll
        for (int k = 0; k < 4; k++) {
            aw[k] = als[c[k]];
            aw[4 + k] = als[c[4 + k]];
            p[k] = H[(c[k] << 6) + lane];
            p[4 + k] = H[(c[4 + k] << 6) + lane];
        }
        #pragma unroll
        for (int k = 0; k < 4; k++) {
            float e = aw[k] + aldA; e = LRELU(e); float w = __expf(e);
            sA += w; aA += w * bf2f(p[k]);
            float e2 = aw[4 + k] + aldB; e2 = LRELU(e2); float w2 = __expf(e2);
            sB += w2; aB += w2 * bf2f(p[4 + k]);
        }
        jA += 4; jB += 4;
    }
    for (; jA + 4 <= endA; jA += 4) {
        int c[4]; float aw[4]; unsigned short p[4];
        #pragma unroll
        for (int k = 0; k < 4; k++) c[k] = col[jA + k];
        #pragma unroll
        for (int k = 0; k < 4; k++) { aw[k] = als[c[k]]; p[k] = H[(c[k] << 6) + lane]; }
        #pragma unroll
        for (int k = 0; k < 4; k++) {
            float e = aw[k] + aldA; e = LRELU(e); float w = __expf(e);
            sA += w; aA += w * bf2f(p[k]);
        }
    }
    for (; jA < endA; jA++) {
        int cc = col[jA];
        float e = als[cc] + aldA; e = LRELU(e); float w = __expf(e);
        sA += w; aA += w * bf2f(H[(cc << 6) + lane]);
    }
    for (; jB + 4 <= endB; jB += 4) {
        int c[4]; float aw[4]; unsigned short p[4];
        #pragma unroll
        for (int k = 0; k < 4; k++) c[k] = col[jB + k];
        #pragma unroll
        for (int k = 0; k < 4; k++) { aw[k] = als[c[k]]; p[k] = H[(c[k] << 6) + lane]; }
        #pragma unroll
        for (int k = 0; k < 4; k++) {
            float e = aw[k] + aldB; e = LRELU(e); float w = __expf(e);
            sB += w; aB += w * bf2f(p[k]);
        }
    }
    for (; jB < endB; jB++) {
        int cc = col[jB];
        float e = als[cc] + aldB; e = LRELU(e); float w = __expf(e);
        sB += w; aB += w * bf2f(H[(cc << 6) + lane]);
    }

    if (vA) {
        float v = aA / (sA + 1e-16f) + b2[lane];
        float su = v, sq = v * v;
        #pragma unroll
        for (int off = 32; off; off >>= 1) {
            su += __shfl_xor(su, off, 64);
            sq += __shfl_xor(sq, off, 64);
        }
        float mu = su * (1.f / 64.f);
        float var = sq * (1.f / 64.f) - mu * mu;
        float r = rsqrtf(var + 1e-5f);
        out[(size_t)nodeA * 64 + lane] = (v - mu) * r * lng[lane] + lnb[lane];
    }
    if (vB) {
        float v = aB / (sB + 1e-16f) + b2[lane];
        float su = v, sq = v * v;
        #pragma unroll
        for (int off = 32; off; off >>= 1) {
            su += __shfl_xor(su, off, 64);
            sq += __shfl_xor(sq, off, 64);
        }
        float mu = su * (1.f / 64.f);
        float var = sq * (1.f / 64.f) - mu * mu;
        float r = rsqrtf(var + 1e-5f);
        out[(size_t)nodeB * 64 + lane] = (v - mu) * r * lng[lane] + lnb[lane];
    }
}

// ---------------- launch ----------------

extern "C" void kernel_launch(void* const* d_in, const int* in_sizes, int n_in,
                              void* d_out, int out_size, void* d_ws, size_t ws_size,
                              hipStream_t stream) {
    const float* x   = (const float*)d_in[0];
    const int*   ei  = (const int*)d_in[1];
    const float* W0  = (const float*)d_in[2];
    const float* as0 = (const float*)d_in[3];
    const float* ad0 = (const float*)d_in[4];
    const float* b0  = (const float*)d_in[5];
    const float* g0  = (const float*)d_in[6];
    const float* bt0 = (const float*)d_in[7];
    const float* W1  = (const float*)d_in[8];
    const float* as1 = (const float*)d_in[9];
    const float* ad1 = (const float*)d_in[10];
    const float* b1  = (const float*)d_in[11];
    const float* g1  = (const float*)d_in[12];
    const float* bt1 = (const float*)d_in[13];
    const float* W2  = (const float*)d_in[14];
    const float* as2 = (const float*)d_in[15];
    const float* ad2 = (const float*)d_in[16];
    const float* b2  = (const float*)d_in[17];
    const float* lng = (const float*)d_in[18];
    const float* lnb = (const float*)d_in[19];

    const int N = in_sizes[0] / 128;
    const int E = in_sizes[1] / 2;
    const int Etot = E + N;
    const int nb = (N + 127) >> 7;     // buckets of 128 nodes (requires nb <= 1024)

    char* p = (char*)d_ws;
    auto carve = [&](size_t bytes) {
        void* q = (void*)p;
        p += (bytes + 255) & ~(size_t)255;
        return q;
    };
    short* Hb     = (short*)carve((size_t)N * 128 * 2);
    short* aggb   = (short*)carve((size_t)N * 128 * 2);
    short* x1b    = (short*)carve((size_t)N * 128 * 2);
    float* als    = (float*)carve((size_t)N * 8 * 4);
    float* ald    = (float*)carve((size_t)N * 8 * 4);
    int*   rowptr = (int*)carve((size_t)(N + 1) * 4);
    // deg + part adjacent -> one memset
    const size_t degpad = ((size_t)N * 4 + 255) & ~(size_t)255;
    int*   deg    = (int*)carve(degpad);
    float* part   = (float*)carve(64 * 256 * 4);
    int*   col    = (int*)carve((size_t)Etot * 4);
    int2*  ebin   = (int2*)carve((size_t)E * 8);
    int*   bcursor= (int*)carve(1024 * 4);
    float2* ss    = (float2*)carve(128 * 8);
    short* Wt0    = (short*)carve(144 * 128 * 2);
    short* Wt1    = (short*)carve(144 * 128 * 2);
    short* Wt2    = (short*)carve(80 * 128 * 2);
    int*   partial= (int*)carve(256 * 4);

    const float invN = 1.f / (float)N;
    const int eb = (E + N + 255) / 256;
    const int nsb = (N + SC - 1) / SC;

    hipMemsetAsync(deg, 0, degpad + 64 * 256 * 4, stream);
    k_count_wprep<<<eb, 256, 0, stream>>>(ei + E, E, N, deg, W0, W1, W2,
                                          as0, ad0, as1, ad1, as2, ad2, Wt0, Wt1, Wt2);
    k_scan1<<<nsb, 256, 0, stream>>>(deg, N, partial);
    k_scan2<<<1, 256, 0, stream>>>(partial, nsb);
    k_scan3<<<nsb, 256, 0, stream>>>(deg, N, Etot, partial, rowptr, bcursor);
    const int bb = (E + 256 * EPT - 1) / (256 * EPT);
    k_bin<<<bb, 256, 0, stream>>>(ei, ei + E, E, nb, bcursor, ebin);
    k_cfill<<<nb, 256, 0, stream>>>(rowptr, ebin, col, N);

    const int gb = (N + 127) / 128;
    const int ab = (N + 7) / 8;

    // ---- layer 0 ----
    k_gemm<128, false, false, false><<<gb, 256, 0, stream>>>(x, Wt0, Hb, nullptr, nullptr,
                                                             nullptr, als, ald, N);
    k_agg<<<ab, 256, 0, stream>>>(rowptr, col, Hb, als, ald, b0, aggb, part, N);
    k_bnreduce<<<1, 128, 0, stream>>>(part, g0, bt0, invN, ss);

    // ---- layer 1 (BN-apply fused into GEMM staging; agg/x1 bf16) ----
    k_gemm<128, true, false, true><<<gb, 256, 0, stream>>>(aggb, Wt1, Hb, ss, x, x1b,
                                                           als, ald, N);
    k_agg<<<ab, 256, 0, stream>>>(rowptr, col, Hb, als, ald, b1, aggb, part, N);
    k_bnreduce<<<1, 128, 0, stream>>>(part, g1, bt1, invN, ss);

    // ---- layer 2 (BN-apply fused; bf16 residual; x2 never materialized) ----
    k_gemm<64, true, true, false><<<gb, 256, 0, stream>>>(aggb, Wt2, Hb, ss, x1b, nullptr,
                                                          als, ald, N);
    k_agg2ln<<<ab, 256, 0, stream>>>(rowptr, col, Hb, als, ald, b2, lng, lnb,
                                     (float*)d_out, N);
}